// Round 1
// baseline (43.339 us; speedup 1.0000x reference)
//
#include <hip/hip_runtime.h>
#include <cstdint>

constexpr int P   = 32;
constexpr int RES = 256;
constexpr int H   = 480;
constexpr int W   = 640;
constexpr int BLK = 256;   // 16x16 pixel tile

__device__ __forceinline__ uint32_t mono_key(float f) {
    uint32_t b = __float_as_uint(f);
    return (b & 0x80000000u) ? ~b : (b | 0x80000000u);
}
__device__ __forceinline__ float unmono(uint32_t m) {
    uint32_t b = (m & 0x80000000u) ? (m ^ 0x80000000u) : ~m;
    return __uint_as_float(b);
}

__global__ __launch_bounds__(256) void render_kernel(
    const float* __restrict__ content,  // (P,4,256,256)
    const float* __restrict__ basis,    // (P,3,3)
    const float* __restrict__ ppos,     // (P,3)
    const float* __restrict__ pwh,      // (P,2)
    const float* __restrict__ camR,     // (3,3)
    const float* __restrict__ camT,     // (3,)
    float* __restrict__ out)            // (H,W,4)
{
    // per-thread sorted hit list in LDS, [entry][tid] so lanes are contiguous
    __shared__ uint32_t s_key[P][BLK];
    __shared__ uint8_t  s_idx[P][BLK];

    const int t = threadIdx.x;
    const int x = blockIdx.x * 16 + (t & 15);
    const int y = blockIdx.y * 16 + (t >> 4);

    // camera (uniform)
    const float R0=camR[0],R1=camR[1],R2=camR[2],
                R3=camR[3],R4=camR[4],R5=camR[5],
                R6=camR[6],R7=camR[7],R8=camR[8];
    const float T0=camT[0],T1=camT[1],T2=camT[2];
    const float cpx = -(R0*T0 + R3*T1 + R6*T2);
    const float cpy = -(R1*T0 + R4*T1 + R7*T2);
    const float cpz = -(R2*T0 + R5*T1 + R8*T2);

    // ray dir (FOCAL = 1): same op order as reference for bit-compat
    const float gx = ((float)x + 0.5f) / (float)W * 2.0f - 1.0f;
    const float gy = ((float)y + 0.5f) / (float)H * 2.0f - 1.0f;
    const float dwx = gx*R0 + gy*R3 + R6;
    const float dwy = gx*R1 + gy*R4 + R7;
    const float dwz = gx*R2 + gy*R5 + R8;

    // ---- pass 1: geometry only; insertion-sort in-plane hits ----
    int cnt = 0;
    for (int p = 0; p < P; ++p) {
        const float b00 = basis[p*9+0], b01 = basis[p*9+1], n0 = basis[p*9+2];
        const float b10 = basis[p*9+3], b11 = basis[p*9+4], n1 = basis[p*9+5];
        const float b20 = basis[p*9+6], b21 = basis[p*9+7], n2 = basis[p*9+8];
        const float px = ppos[p*3+0], py = ppos[p*3+1], pz = ppos[p*3+2];
        const float hw0 = pwh[p*2+0]*0.5f, hw1 = pwh[p*2+1]*0.5f;

        const float num = n0*(px-cpx) + n1*(py-cpy) + n2*(pz-cpz);
        float den = n0*dwx + n1*dwy + n2*dwz;
        if (fabsf(den) < 1e-6f) den = 1e-6f;
        const float depth = num / den;          // IEEE divide: exact ordering

        const float ox = cpx + depth*dwx - px;
        const float oy = cpy + depth*dwy - py;
        const float oz = cpz + depth*dwz - pz;
        const float u = (ox*b00 + oy*b10 + oz*b20) / hw0;
        const float v = (ox*b01 + oy*b11 + oz*b21) / hw1;

        if (fabsf(u) <= 1.0f && fabsf(v) <= 1.0f) {
            const uint32_t k = mono_key(depth);
            int j = cnt;
            while (j > 0 && s_key[j-1][t] > k) {
                s_key[j][t] = s_key[j-1][t];
                s_idx[j][t] = s_idx[j-1][t];
                --j;
            }
            s_key[j][t] = k;
            s_idx[j][t] = (uint8_t)p;
            ++cnt;
        }
    }

    // ---- pass 2: walk sorted hits, sample + composite ----
    float aR = 0.f, aG = 0.f, aB = 0.f, aD = 0.f, tr = 1.f;
    for (int i = 0; i < cnt; ++i) {
        const uint32_t k = s_key[i][t];
        const int p = (int)s_idx[i][t];
        const float depth = unmono(k);          // bit-exact pass-1 depth

        const float b00 = basis[p*9+0], b01 = basis[p*9+1];
        const float b10 = basis[p*9+3], b11 = basis[p*9+4];
        const float b20 = basis[p*9+6], b21 = basis[p*9+7];
        const float px = ppos[p*3+0], py = ppos[p*3+1], pz = ppos[p*3+2];
        const float hw0 = pwh[p*2+0]*0.5f, hw1 = pwh[p*2+1]*0.5f;

        const float ox = cpx + depth*dwx - px;
        const float oy = cpy + depth*dwy - py;
        const float oz = cpz + depth*dwz - pz;
        const float u = (ox*b00 + oy*b10 + oz*b20) / hw0;
        const float v = (ox*b01 + oy*b11 + oz*b21) / hw1;

        // bilinear setup (matches reference: x=(u+1)*Wc*0.5-0.5)
        const float fx = (u + 1.0f) * 128.0f - 0.5f;
        const float fy = (v + 1.0f) * 128.0f - 0.5f;
        const float x0f = floorf(fx), y0f = floorf(fy);
        const float wx = fx - x0f, wy = fy - y0f;
        const int ix = (int)x0f, iy = (int)y0f;

        const int x0c = min(max(ix,     0), RES-1);
        const int x1c = min(max(ix + 1, 0), RES-1);
        const int y0c = min(max(iy,     0), RES-1);
        const int y1c = min(max(iy + 1, 0), RES-1);
        const float mx0 = (ix     >= 0 && ix     < RES) ? 1.f : 0.f;
        const float mx1 = (ix + 1 >= 0 && ix + 1 < RES) ? 1.f : 0.f;
        const float my0 = (iy     >= 0 && iy     < RES) ? 1.f : 0.f;
        const float my1 = (iy + 1 >= 0 && iy + 1 < RES) ? 1.f : 0.f;
        const float m00 = mx0 * my0, m01 = mx1 * my0;
        const float m10 = mx0 * my1, m11 = mx1 * my1;

        const int o00 = y0c * RES + x0c, o01 = y0c * RES + x1c;
        const int o10 = y1c * RES + x0c, o11 = y1c * RES + x1c;
        const float* pc = content + ((size_t)p << 18);   // p*4*65536

        float c4[4];
        #pragma unroll
        for (int c = 0; c < 4; ++c) {
            const float* ic = pc + (c << 16);
            const float v00 = ic[o00] * m00;
            const float v01 = ic[o01] * m01;
            const float v10 = ic[o10] * m10;
            const float v11 = ic[o11] * m11;
            const float top = v00 * (1.f - wx) + v01 * wx;
            const float bot = v10 * (1.f - wx) + v11 * wx;
            const float raw = top * (1.f - wy) + bot * wy;
            c4[c] = 1.0f / (1.0f + __expf(-raw));        // sigmoid
        }

        const float wgt = c4[0] * tr;
        aD += depth * wgt;
        aR += c4[1] * wgt;
        aG += c4[2] * wgt;
        aB += c4[3] * wgt;
        tr *= (1.0f - c4[0]);
    }

    const int o = (y * W + x) * 4;
    float4 res; res.x = aR; res.y = aG; res.z = aB; res.w = aD;
    *reinterpret_cast<float4*>(out + o) = res;
}

extern "C" void kernel_launch(void* const* d_in, const int* in_sizes, int n_in,
                              void* d_out, int out_size, void* d_ws, size_t ws_size,
                              hipStream_t stream) {
    const float* content = (const float*)d_in[0];
    const float* basis   = (const float*)d_in[1];
    const float* ppos    = (const float*)d_in[2];
    const float* pwh     = (const float*)d_in[3];
    const float* camR    = (const float*)d_in[4];
    const float* camT    = (const float*)d_in[5];

    dim3 grid(W / 16, H / 16);   // 40 x 30 blocks, 256 threads = 16x16 pixels
    render_kernel<<<grid, dim3(BLK), 0, stream>>>(
        content, basis, ppos, pwh, camR, camT, (float*)d_out);
}